// Round 5
// baseline (297.112 us; speedup 1.0000x reference)
//
#include <hip/hip_runtime.h>
#include <hip/hip_bf16.h>
#include <stdint.h>

// Problem constants
#define D_DIM 512
#define K_CB  4096
#define N_TOK 16384
#define TOPK  8

// Fused kernel: 64 tokens/block, 1024 threads (16 waves), 8 passes of 512 centroids
#define TOKB  64
#define NPASS 8

typedef __attribute__((ext_vector_type(8)))  short bf16x8;
typedef __attribute__((ext_vector_type(16))) float f32x16;
typedef __attribute__((ext_vector_type(4)))  float f32x4;

__device__ __forceinline__ unsigned short f2bf(float f) {
    union { float f; unsigned u; } v; v.f = f;
    unsigned r = (v.u + 0x7fffu + ((v.u >> 16) & 1u)) >> 16;  // RNE
    return (unsigned short)r;
}

// sortable key: 20 high bits = order-preserving float map, 12 low bits = 4095-idx
__device__ __forceinline__ unsigned int mkkey(float s, unsigned int idxc) {
    unsigned int u = __float_as_uint(s);
    unsigned int k = u ^ ((unsigned int)((int)u >> 31) | 0x80000000u);
    return (k & 0xFFFFF000u) | idxc;
}

// branchless top-8 insert: 8x (v_max_u32 + v_min_u32)
__device__ __forceinline__ void inskey(unsigned int k, unsigned int (&ts)[8]) {
    #pragma unroll
    for (int q = 0; q < 8; ++q) {
        unsigned int hi = ts[q] > k ? ts[q] : k;
        unsigned int lo = ts[q] > k ? k : ts[q];
        ts[q] = hi; k = lo;
    }
}

// cbf = bf16(codebook) in MFMA-A-fragment order, via LDS (coalesced in AND out).
// Element (row,d): d = ks*16 + h*8 + j -> cbf[ (row>>5)*16384 + ks*512 + (h*32+(row&31))*8 + j ]
__global__ __launch_bounds__(256) void conv_cb_kernel(
    const float* __restrict__ cb, unsigned short* __restrict__ cbf,
    float* __restrict__ cnorm, float* __restrict__ loss) {
    __shared__ unsigned short ls[32 * 512];          // 32 KB staged fragment tile
    const int t = threadIdx.x, g32 = blockIdx.x;     // g32: 32-row group 0..127
    if (g32 == 0 && t == 0) *loss = 0.f;
    const int row32 = t >> 3;
    float sq = 0.f;
    #pragma unroll
    for (int i = 0; i < 8; ++i) {
        const int gg = (t & 7) + 8 * i;              // 8-float granule index 0..63
        const float* src = cb + ((size_t)(g32 * 32 + row32)) * D_DIM + gg * 8;
        float4 a = ((const float4*)src)[0], b = ((const float4*)src)[1];
        ushort4 o0, o1;
        o0.x = f2bf(a.x); o0.y = f2bf(a.y); o0.z = f2bf(a.z); o0.w = f2bf(a.w);
        o1.x = f2bf(b.x); o1.y = f2bf(b.y); o1.z = f2bf(b.z); o1.w = f2bf(b.w);
        const int li = (gg >> 1) * 512 + ((gg & 1) * 32 + row32) * 8;
        *(ushort4*)&ls[li]     = o0;
        *(ushort4*)&ls[li + 4] = o1;
        sq += a.x*a.x + a.y*a.y + a.z*a.z + a.w*a.w
            + b.x*b.x + b.y*b.y + b.z*b.z + b.w*b.w;
    }
    sq += __shfl_down(sq, 4, 8);
    sq += __shfl_down(sq, 2, 8);
    sq += __shfl_down(sq, 1, 8);
    if ((t & 7) == 0) cnorm[g32 * 32 + row32] = sq;
    __syncthreads();
    #pragma unroll
    for (int j = 0; j < 8; ++j) {                    // 32 KB contiguous coalesced write
        const int s = j * 256 + t;
        *(ushort4*)(cbf + (size_t)g32 * 16384 + s * 8)     = *(const ushort4*)&ls[s * 8];
        *(ushort4*)(cbf + (size_t)g32 * 16384 + s * 8 + 4) = *(const ushort4*)&ls[s * 8 + 4];
    }
}

// Fused: A = centroids (coalesced fragment-ordered global), B = tokens (LDS swizzled),
// register-resident key selection; 16 waves/CU for latency hiding; nt streams.
__global__ __launch_bounds__(1024) void vq_fused(
    const float* __restrict__ x, const float* __restrict__ cb,
    const unsigned short* __restrict__ cbf, const float* __restrict__ cnorm,
    float* __restrict__ out, float* __restrict__ loss_acc)
{
    __shared__ union {
        unsigned short xs[TOKB * D_DIM];             // 65536 B: bf16(2x), swizzled
        unsigned int keys[256 * 64];                 // 65536 B: [list*8+e][token]
    } u;
    __shared__ unsigned int pk[64 * 32];             // 8 KB: stage-1 merge partials
    __shared__ int   tki[TOKB * TOPK];
    __shared__ float tks[TOKB * TOPK];
    __shared__ float tkw[TOKB * TOPK];
    __shared__ float redbuf[16];

    const int t    = threadIdx.x;
    const int lane = t & 63;
    const int w    = t >> 6;          // wave 0..15
    const int m32  = lane & 31;
    const int half = lane >> 5;
    const int tok0 = blockIdx.x * TOKB;

    // ---- stage xs = bf16(2x), XOR-swizzled granules, nt loads ----
    #pragma unroll
    for (int i = 0; i < 4; ++i) {
        const int s = i * 1024 + t, row = s >> 6, gp = s & 63;
        const int g = (gp & 56) | ((gp & 7) ^ (row & 7));
        const f32x4* src = (const f32x4*)&x[(size_t)(tok0 + row) * D_DIM + g * 8];
        f32x4 v0 = __builtin_nontemporal_load(src);
        f32x4 v1 = __builtin_nontemporal_load(src + 1);
        ushort4 o0, o1;
        o0.x = f2bf(2.f*v0.x); o0.y = f2bf(2.f*v0.y); o0.z = f2bf(2.f*v0.z); o0.w = f2bf(2.f*v0.w);
        o1.x = f2bf(2.f*v1.x); o1.y = f2bf(2.f*v1.y); o1.z = f2bf(2.f*v1.z); o1.w = f2bf(2.f*v1.w);
        *(ushort4*)&u.xs[s * 8]     = o0;
        *(ushort4*)&u.xs[s * 8 + 4] = o1;
    }
    __syncthreads();

    unsigned int ts0[8], ts1[8];      // token m32 / token 32+m32
    #pragma unroll
    for (int i = 0; i < 8; ++i) { ts0[i] = 0u; ts1[i] = 0u; }

    const char* cf = (const char*)cbf;
    for (int pass = 0; pass < NPASS; ++pass) {
        const int rowbase = pass * 512 + w * 32;     // this wave's 32 centroids
        f32x16 acc0, acc1;
        #pragma unroll
        for (int g = 0; g < 4; ++g) {                // acc init = -||c||^2
            float4 v = *(const float4*)&cnorm[rowbase + g * 8 + 4 * half];
            acc0[g*4+0] = -v.x; acc0[g*4+1] = -v.y; acc0[g*4+2] = -v.z; acc0[g*4+3] = -v.w;
            acc1[g*4+0] = -v.x; acc1[g*4+1] = -v.y; acc1[g*4+2] = -v.z; acc1[g*4+3] = -v.w;
        }
        const char* abase = cf + (size_t)(pass * 16 + w) * 32768 + lane * 16;
        #pragma unroll 8
        for (int ks = 0; ks < 32; ++ks) {
            bf16x8 A = *(const bf16x8*)(abase + ks * 1024);
            const int gf = ks * 2 + half;
            const int slot = (gf & 56) | ((gf & 7) ^ (m32 & 7));
            bf16x8 B0 = *(const bf16x8*)&u.xs[m32 * D_DIM + slot * 8];
            bf16x8 B1 = *(const bf16x8*)&u.xs[(32 + m32) * D_DIM + slot * 8];
            acc0 = __builtin_amdgcn_mfma_f32_32x32x16_bf16(A, B0, acc0, 0, 0, 0);
            acc1 = __builtin_amdgcn_mfma_f32_32x32x16_bf16(A, B1, acc1, 0, 0, 0);
        }
        const unsigned int K0 = (unsigned int)(4095 - rowbase - 4 * half);
        #pragma unroll
        for (int r = 0; r < 16; ++r) {
            const unsigned int cr = (unsigned int)((r & 3) + 8 * (r >> 2));
            inskey(mkkey(acc0[r], K0 - cr), ts0);
            inskey(mkkey(acc1[r], K0 - cr), ts1);
        }
    }

    // ---- epilogue ----
    __syncthreads();   // xs dead -> keys
    {
        const int kk = (w * 2 + half) * 8;           // list id 0..31, 8 keys each
        #pragma unroll
        for (int e = 0; e < 8; ++e) {
            u.keys[(kk + e) * 64 + m32]      = ts0[e];
            u.keys[(kk + e) * 64 + 32 + m32] = ts1[e];
        }
    }
    __syncthreads();
    if (t < 256) {     // stage 1: 4 threads/token, 64 keys each
        const int token = t >> 2, sub = t & 3;
        unsigned int bs[8];
        #pragma unroll
        for (int i = 0; i < 8; ++i) bs[i] = 0u;
        #pragma unroll 4
        for (int k = 0; k < 64; ++k) inskey(u.keys[(sub * 64 + k) * 64 + token], bs);
        #pragma unroll
        for (int e = 0; e < 8; ++e) pk[token * 32 + sub * 8 + e] = bs[e];
    }
    __syncthreads();
    if (t < TOKB) {    // stage 2: final top-8, decode indices
        unsigned int bs[8];
        #pragma unroll
        for (int i = 0; i < 8; ++i) bs[i] = 0u;
        #pragma unroll 4
        for (int k = 0; k < 32; ++k) inskey(pk[t * 32 + k], bs);
        #pragma unroll
        for (int r = 0; r < TOPK; ++r) tki[t * TOPK + r] = 4095 - (int)(bs[r] & 0xFFFu);
    }
    __syncthreads();
    {   // exact fp32 rescore: 2 threads per (token, entry), half-D each
        const int token = t >> 4, e = (t >> 1) & 7, dh = t & 1;
        const int idx = tki[token * TOPK + e];
        const float4* xr = (const float4*)(x + (size_t)(tok0 + token) * D_DIM) + dh * 64;
        const float4* cr = (const float4*)(cb + (size_t)idx * D_DIM) + dh * 64;
        float dot = 0.f;
        #pragma unroll 4
        for (int i = 0; i < 64; ++i) {
            float4 xv = xr[i], cv = cr[i];
            dot += xv.x*cv.x + xv.y*cv.y + xv.z*cv.z + xv.w*cv.w;
        }
        dot += __shfl_xor(dot, 1, 64);
        if (dh == 0) tks[token * TOPK + e] = 2.f * dot - cnorm[idx];
    }
    __syncthreads();
    if (t < TOKB) {    // softmax over the 8
        float m = -1e38f;
        #pragma unroll
        for (int e = 0; e < TOPK; ++e) m = fmaxf(m, tks[t*TOPK+e]);
        float sum = 0.f, wv[TOPK];
        #pragma unroll
        for (int e = 0; e < TOPK; ++e) { wv[e] = __expf(tks[t*TOPK+e] - m); sum += wv[e]; }
        const float inv = 1.f / sum;
        #pragma unroll
        for (int e = 0; e < TOPK; ++e) tkw[t*TOPK+e] = wv[e] * inv;
    }
    __syncthreads();
    // output + loss partial (x nt-read once, out nt-write)
    float lsum = 0.f;
    #pragma unroll 1
    for (int it = 0; it < (TOKB * (D_DIM / 4)) / 1024; ++it) {   // 8 iters
        const int p = it * 1024 + t;
        const int token = p >> 7, d4 = p & 127;
        float4 q = {0.f, 0.f, 0.f, 0.f};
        #pragma unroll
        for (int e = 0; e < TOPK; ++e) {
            const float wv = tkw[token * TOPK + e];
            const int  idx = tki[token * TOPK + e];
            const float4 cv = ((const float4*)cb)[(size_t)idx * (D_DIM / 4) + d4];
            q.x += wv * cv.x; q.y += wv * cv.y; q.z += wv * cv.z; q.w += wv * cv.w;
        }
        const size_t go = (size_t)(tok0 + token) * (D_DIM / 4) + d4;
        f32x4 xv = __builtin_nontemporal_load((const f32x4*)x + go);
        const float ex = q.x - xv.x, ey = q.y - xv.y, ez = q.z - xv.z, ew = q.w - xv.w;
        lsum += ex*ex + ey*ey + ez*ez + ew*ew;
        f32x4 qv = {q.x, q.y, q.z, q.w};
        __builtin_nontemporal_store(qv, (f32x4*)out + go);
    }
    #pragma unroll
    for (int off = 32; off > 0; off >>= 1) lsum += __shfl_down(lsum, off, 64);
    if (lane == 0) redbuf[w] = lsum;
    __syncthreads();
    if (t == 0) {
        float s = 0.f;
        #pragma unroll
        for (int i = 0; i < 16; ++i) s += redbuf[i];
        atomicAdd(loss_acc, s);
    }
}

__global__ void finalize_kernel(const float* __restrict__ loss_acc,
                                float* __restrict__ out) {
    out[(size_t)N_TOK * D_DIM] = 1.25f * loss_acc[0] / (float)((size_t)N_TOK * D_DIM);
}

extern "C" void kernel_launch(void* const* d_in, const int* in_sizes, int n_in,
                              void* d_out, int out_size, void* d_ws, size_t ws_size,
                              hipStream_t stream) {
    const float* x  = (const float*)d_in[0];   // [8,2048,512] fp32
    const float* cb = (const float*)d_in[1];   // [4096,512] fp32
    float* out = (float*)d_out;

    char* ws = (char*)d_ws;
    unsigned short* cbf   = (unsigned short*)ws;            // 4 MB, fragment-ordered
    float*          cnorm = (float*)(ws + 4194304);         // 16 KB
    float*          loss  = (float*)(ws + 4210688);         // 4 B

    conv_cb_kernel<<<128, 256, 0, stream>>>(cb, cbf, cnorm, loss);
    vq_fused<<<N_TOK / TOKB, 1024, 0, stream>>>(x, cb, cbf, cnorm, out, loss);
    finalize_kernel<<<1, 1, 0, stream>>>(loss, out);
}

// Round 6
// 256.896 us; speedup vs baseline: 1.1565x; 1.1565x over previous
//
#include <hip/hip_runtime.h>
#include <hip/hip_bf16.h>
#include <stdint.h>

// Problem constants
#define D_DIM 512
#define K_CB  4096
#define N_TOK 16384
#define TOPK  8

// Fused kernel: 64 tokens/block, 1024 threads (16 waves), 4 passes of 1024 centroids
#define TOKB  64
#define NPASS 4

typedef __attribute__((ext_vector_type(8)))  short          bf16x8;
typedef __attribute__((ext_vector_type(8)))  unsigned short us8;
typedef __attribute__((ext_vector_type(16))) float          f32x16;
typedef __attribute__((ext_vector_type(4)))  float          f32x4;

__device__ __forceinline__ unsigned short f2bf(float f) {
    union { float f; unsigned u; } v; v.f = f;
    unsigned r = (v.u + 0x7fffu + ((v.u >> 16) & 1u)) >> 16;  // RNE
    return (unsigned short)r;
}

// branchless top-8 insert: 8x (v_max_u32 + v_min_u32)
__device__ __forceinline__ void inskey(unsigned int k, unsigned int (&ts)[8]) {
    #pragma unroll
    for (int q = 0; q < 8; ++q) {
        unsigned int hi = ts[q] > k ? ts[q] : k;
        unsigned int lo = ts[q] > k ? k : ts[q];
        ts[q] = hi; k = lo;
    }
}

// cbf = bf16(codebook) in MFMA-A-fragment order, via LDS (coalesced in AND out).
__global__ __launch_bounds__(256) void conv_cb_kernel(
    const float* __restrict__ cb, unsigned short* __restrict__ cbf,
    float* __restrict__ cnorm, float* __restrict__ loss,
    unsigned int* __restrict__ ticket) {
    __shared__ unsigned short ls[32 * 512];          // 32 KB staged fragment tile
    const int t = threadIdx.x, g32 = blockIdx.x;     // g32: 32-row group 0..127
    if (g32 == 0 && t == 0) { *loss = 0.f; *ticket = 0u; }
    const int row32 = t >> 3;
    float sq = 0.f;
    #pragma unroll
    for (int i = 0; i < 8; ++i) {
        const int gg = (t & 7) + 8 * i;              // 8-float granule index 0..63
        const float* src = cb + ((size_t)(g32 * 32 + row32)) * D_DIM + gg * 8;
        float4 a = ((const float4*)src)[0], b = ((const float4*)src)[1];
        ushort4 o0, o1;
        o0.x = f2bf(a.x); o0.y = f2bf(a.y); o0.z = f2bf(a.z); o0.w = f2bf(a.w);
        o1.x = f2bf(b.x); o1.y = f2bf(b.y); o1.z = f2bf(b.z); o1.w = f2bf(b.w);
        const int li = (gg >> 1) * 512 + ((gg & 1) * 32 + row32) * 8;
        *(ushort4*)&ls[li]     = o0;
        *(ushort4*)&ls[li + 4] = o1;
        sq += a.x*a.x + a.y*a.y + a.z*a.z + a.w*a.w
            + b.x*b.x + b.y*b.y + b.z*b.z + b.w*b.w;
    }
    sq += __shfl_down(sq, 4, 8);
    sq += __shfl_down(sq, 2, 8);
    sq += __shfl_down(sq, 1, 8);
    if ((t & 7) == 0) cnorm[g32 * 32 + row32] = sq;
    __syncthreads();
    #pragma unroll
    for (int j = 0; j < 8; ++j) {                    // 32 KB contiguous coalesced write
        const int s = j * 256 + t;
        *(ushort4*)(cbf + (size_t)g32 * 16384 + s * 8)     = *(const ushort4*)&ls[s * 8];
        *(ushort4*)(cbf + (size_t)g32 * 16384 + s * 8 + 4) = *(const ushort4*)&ls[s * 8 + 4];
    }
}

// Fused: A = centroids (coalesced fragment-ordered global), B = tokens (LDS,
// fragment-ordered: conflict-free b128 reads AND writes), biased-key selection
// on accumulator registers; last-block ticket writes the loss scalar.
__global__ __launch_bounds__(1024) void vq_fused(
    const float* __restrict__ x, const float* __restrict__ cb,
    const unsigned short* __restrict__ cbf, const float* __restrict__ cnorm,
    float* __restrict__ out, float* __restrict__ loss_acc,
    unsigned int* __restrict__ ticket)
{
    __shared__ union {
        unsigned short xs[TOKB * D_DIM];             // 65536 B: bf16(2x), B-fragment order
        unsigned int keys[256 * 64];                 // 65536 B: [list*8+e][token]
    } u;
    __shared__ float ncn[K_CB];                      // 16384 B: 64 - ||c||^2
    __shared__ unsigned int pk[64 * 32];             // 8 KB: stage-1 merge partials
    __shared__ int   tki[TOKB * TOPK];
    __shared__ float tks[TOKB * TOPK];
    __shared__ float tkw[TOKB * TOPK];
    __shared__ float redbuf[16];

    const int t    = threadIdx.x;
    const int lane = t & 63;
    const int w    = t >> 6;          // wave 0..15
    const int m32  = lane & 31;
    const int half = lane >> 5;
    const int tok0 = blockIdx.x * TOKB;

    // ---- stage xs in B-fragment order: lane = token row, 64 B per load ----
    // elem(tok,d): ks=d>>4, khalf=(d>>3)&1, j=d&7 -> xs[(tok>>5)*16384 + ks*512
    //   + ((khalf*32)+(tok&31))*8 + j]
    #pragma unroll
    for (int i = 0; i < 2; ++i) {
        const int gg0 = i * 32 + w * 2;              // even granule; pair (gg0, gg0+1)
        const float* src = x + (size_t)(tok0 + lane) * D_DIM + gg0 * 8;
        f32x4 v0 = ((const f32x4*)src)[0], v1 = ((const f32x4*)src)[1];
        f32x4 v2 = ((const f32x4*)src)[2], v3 = ((const f32x4*)src)[3];
        us8 o0, o1;
        o0[0] = f2bf(2.f*v0.x); o0[1] = f2bf(2.f*v0.y); o0[2] = f2bf(2.f*v0.z); o0[3] = f2bf(2.f*v0.w);
        o0[4] = f2bf(2.f*v1.x); o0[5] = f2bf(2.f*v1.y); o0[6] = f2bf(2.f*v1.z); o0[7] = f2bf(2.f*v1.w);
        o1[0] = f2bf(2.f*v2.x); o1[1] = f2bf(2.f*v2.y); o1[2] = f2bf(2.f*v2.z); o1[3] = f2bf(2.f*v2.w);
        o1[4] = f2bf(2.f*v3.x); o1[5] = f2bf(2.f*v3.y); o1[6] = f2bf(2.f*v3.z); o1[7] = f2bf(2.f*v3.w);
        const int di = (lane >> 5) * 16384 + (gg0 >> 1) * 512 + (lane & 31) * 8;
        *(us8*)&u.xs[di]       = o0;     // khalf 0
        *(us8*)&u.xs[di + 256] = o1;     // khalf 1
    }
    {   // ncn = 64 - ||c||^2 (bias => scores strictly positive => trivial keys)
        float4 v = ((const float4*)cnorm)[t];
        float4 nv = {64.f - v.x, 64.f - v.y, 64.f - v.z, 64.f - v.w};
        *(float4*)&ncn[t * 4] = nv;
    }
    __syncthreads();

    unsigned int ts0[8], ts1[8];      // token m32 / token 32+m32
    #pragma unroll
    for (int i = 0; i < 8; ++i) { ts0[i] = 0u; ts1[i] = 0u; }

    const char* cf = (const char*)cbf;
    for (int p = 0; p < NPASS; ++p) {
        const int ga = p * 32 + w * 2;               // centroid 32-group pair (ga, ga+1)
        f32x16 a00, a01, a10, a11;
        #pragma unroll
        for (int g = 0; g < 4; ++g) {                // acc init = 64 - ||c||^2 (LDS bcast)
            float4 n0 = *(const float4*)&ncn[ga * 32 + g * 8 + 4 * half];
            float4 n1 = *(const float4*)&ncn[ga * 32 + 32 + g * 8 + 4 * half];
            a00[g*4+0]=n0.x; a00[g*4+1]=n0.y; a00[g*4+2]=n0.z; a00[g*4+3]=n0.w;
            a01[g*4+0]=n0.x; a01[g*4+1]=n0.y; a01[g*4+2]=n0.z; a01[g*4+3]=n0.w;
            a10[g*4+0]=n1.x; a10[g*4+1]=n1.y; a10[g*4+2]=n1.z; a10[g*4+3]=n1.w;
            a11[g*4+0]=n1.x; a11[g*4+1]=n1.y; a11[g*4+2]=n1.z; a11[g*4+3]=n1.w;
        }
        const char* ab = cf + (size_t)ga * 32768 + (size_t)lane * 16;
        #pragma unroll 8
        for (int ks = 0; ks < 32; ++ks) {
            bf16x8 A0 = *(const bf16x8*)(ab + (size_t)ks * 1024);
            bf16x8 A1 = *(const bf16x8*)(ab + 32768 + (size_t)ks * 1024);
            bf16x8 B0 = *(const bf16x8*)&u.xs[ks * 512 + lane * 8];           // conflict-free
            bf16x8 B1 = *(const bf16x8*)&u.xs[16384 + ks * 512 + lane * 8];
            a00 = __builtin_amdgcn_mfma_f32_32x32x16_bf16(A0, B0, a00, 0, 0, 0);
            a01 = __builtin_amdgcn_mfma_f32_32x32x16_bf16(A0, B1, a01, 0, 0, 0);
            a10 = __builtin_amdgcn_mfma_f32_32x32x16_bf16(A1, B0, a10, 0, 0, 0);
            a11 = __builtin_amdgcn_mfma_f32_32x32x16_bf16(A1, B1, a11, 0, 0, 0);
        }
        // biased keys: scores in ~[49,76] > 0 => uint-ordered; low 12 bits = 4095-idx
        const unsigned int K0 = 4095u - (unsigned int)(ga * 32) - 4u * (unsigned int)half;
        #pragma unroll
        for (int r = 0; r < 16; ++r) {
            const unsigned int cr = (unsigned int)((r & 3) + 8 * (r >> 2));
            inskey((__float_as_uint(a00[r]) & 0xFFFFF000u) | (K0 - cr),       ts0);
            inskey((__float_as_uint(a01[r]) & 0xFFFFF000u) | (K0 - cr),       ts1);
            inskey((__float_as_uint(a10[r]) & 0xFFFFF000u) | (K0 - 32u - cr), ts0);
            inskey((__float_as_uint(a11[r]) & 0xFFFFF000u) | (K0 - 32u - cr), ts1);
        }
    }

    // ---- epilogue ----
    __syncthreads();   // xs dead -> keys
    {
        const int kk = (w * 2 + half) * 8;           // list id 0..31, 8 keys each
        #pragma unroll
        for (int e = 0; e < 8; ++e) {
            u.keys[(kk + e) * 64 + m32]      = ts0[e];
            u.keys[(kk + e) * 64 + 32 + m32] = ts1[e];
        }
    }
    __syncthreads();
    if (t < 256) {     // stage 1: 4 threads/token, 64 keys each
        const int token = t >> 2, sub = t & 3;
        unsigned int bs[8];
        #pragma unroll
        for (int i = 0; i < 8; ++i) bs[i] = 0u;
        #pragma unroll 4
        for (int k = 0; k < 64; ++k) inskey(u.keys[(sub * 64 + k) * 64 + token], bs);
        #pragma unroll
        for (int e = 0; e < 8; ++e) pk[token * 32 + sub * 8 + e] = bs[e];
    }
    __syncthreads();
    if (t < TOKB) {    // stage 2: final top-8, decode indices
        unsigned int bs[8];
        #pragma unroll
        for (int i = 0; i < 8; ++i) bs[i] = 0u;
        #pragma unroll 4
        for (int k = 0; k < 32; ++k) inskey(pk[t * 32 + k], bs);
        #pragma unroll
        for (int r = 0; r < TOPK; ++r) tki[t * TOPK + r] = 4095 - (int)(bs[r] & 0xFFFu);
    }
    __syncthreads();
    {   // exact fp32 rescore: 2 threads per (token, entry), half-D each
        const int token = t >> 4, e = (t >> 1) & 7, dh = t & 1;
        const int idx = tki[token * TOPK + e];
        const float4* xr = (const float4*)(x + (size_t)(tok0 + token) * D_DIM) + dh * 64;
        const float4* cr = (const float4*)(cb + (size_t)idx * D_DIM) + dh * 64;
        float dot = 0.f;
        #pragma unroll 4
        for (int i = 0; i < 64; ++i) {
            float4 xv = xr[i], cv = cr[i];
            dot += xv.x*cv.x + xv.y*cv.y + xv.z*cv.z + xv.w*cv.w;
        }
        dot += __shfl_xor(dot, 1, 64);
        if (dh == 0) tks[token * TOPK + e] = 2.f * dot - cnorm[idx];
    }
    __syncthreads();
    if (t < TOKB) {    // softmax over the 8
        float m = -1e38f;
        #pragma unroll
        for (int e = 0; e < TOPK; ++e) m = fmaxf(m, tks[t*TOPK+e]);
        float sum = 0.f, wv[TOPK];
        #pragma unroll
        for (int e = 0; e < TOPK; ++e) { wv[e] = __expf(tks[t*TOPK+e] - m); sum += wv[e]; }
        const float inv = 1.f / sum;
        #pragma unroll
        for (int e = 0; e < TOPK; ++e) tkw[t*TOPK+e] = wv[e] * inv;
    }
    __syncthreads();
    // output + loss partial
    float lsum = 0.f;
    #pragma unroll 1
    for (int it = 0; it < (TOKB * (D_DIM / 4)) / 1024; ++it) {   // 8 iters
        const int p = it * 1024 + t;
        const int token = p >> 7, d4 = p & 127;
        float4 q = {0.f, 0.f, 0.f, 0.f};
        #pragma unroll
        for (int e = 0; e < TOPK; ++e) {
            const float wv = tkw[token * TOPK + e];
            const int  idx = tki[token * TOPK + e];
            const float4 cv = ((const float4*)cb)[(size_t)idx * (D_DIM / 4) + d4];
            q.x += wv * cv.x; q.y += wv * cv.y; q.z += wv * cv.z; q.w += wv * cv.w;
        }
        const size_t go = (size_t)(tok0 + token) * (D_DIM / 4) + d4;
        f32x4 xv = __builtin_nontemporal_load((const f32x4*)x + go);
        const float ex = q.x - xv.x, ey = q.y - xv.y, ez = q.z - xv.z, ew = q.w - xv.w;
        lsum += ex*ex + ey*ey + ez*ez + ew*ew;
        f32x4 qv = {q.x, q.y, q.z, q.w};
        __builtin_nontemporal_store(qv, (f32x4*)out + go);
    }
    #pragma unroll
    for (int off = 32; off > 0; off >>= 1) lsum += __shfl_down(lsum, off, 64);
    if (lane == 0) redbuf[w] = lsum;
    __syncthreads();
    if (t == 0) {
        float s = 0.f;
        #pragma unroll
        for (int i = 0; i < 16; ++i) s += redbuf[i];
        atomicAdd(loss_acc, s);
        __threadfence();
        unsigned int prev = atomicAdd(ticket, 1u);
        if (prev == (unsigned int)(gridDim.x - 1)) {   // last block finalizes loss
            __threadfence();
            float total = atomicAdd(loss_acc, 0.f);    // coherent read
            out[(size_t)N_TOK * D_DIM] = 1.25f * total / (float)((size_t)N_TOK * D_DIM);
        }
    }
}

extern "C" void kernel_launch(void* const* d_in, const int* in_sizes, int n_in,
                              void* d_out, int out_size, void* d_ws, size_t ws_size,
                              hipStream_t stream) {
    const float* x  = (const float*)d_in[0];   // [8,2048,512] fp32
    const float* cb = (const float*)d_in[1];   // [4096,512] fp32
    float* out = (float*)d_out;

    char* ws = (char*)d_ws;
    unsigned short* cbf    = (unsigned short*)ws;            // 4 MB, fragment-ordered
    float*          cnorm  = (float*)(ws + 4194304);         // 16 KB
    float*          loss   = (float*)(ws + 4210688);         // 4 B
    unsigned int*   ticket = (unsigned int*)(ws + 4210752);  // 4 B

    conv_cb_kernel<<<128, 256, 0, stream>>>(cb, cbf, cnorm, loss, ticket);
    vq_fused<<<N_TOK / TOKB, 1024, 0, stream>>>(x, cb, cbf, cnorm, out, loss, ticket);
}